// Round 1
// baseline (395.429 us; speedup 1.0000x reference)
//
#include <hip/hip_runtime.h>

// Problem constants (from reference)
#define MIN_LEN_SEG_C 19
#define MAX_NUM_SEG_C 7     // 128 // 19 + 1
#define SEG_GRID_C    64
#define MAX_LEN_PAD_C 192
#define C_DIM         80
#define NQ            (C_DIM / 4)   // 20 float4 per frame

// One block per batch row. 448 threads = 7 waves; wave w handles segment w,
// lane i handles grid position i (SEG_GRID == 64 == wavefront size).
__global__ __launch_bounds__(448) void interp_lnr_kernel(
    const float* __restrict__ x,          // (B, 192, 80)
    const int*   __restrict__ len_seq,    // (B,)
    const float* __restrict__ scales,     // (B*7,)
    const int*   __restrict__ len_seg_raw,// (B*7,)
    float*       __restrict__ out)        // (B, 192, 80)
{
    const int b    = blockIdx.x;
    const int tid  = threadIdx.x;
    const int wave = tid >> 6;   // segment index 0..6
    const int lane = tid & 63;   // grid index 0..63

    __shared__ float s_scale[MAX_NUM_SEG_C];
    __shared__ int   s_lenseg[MAX_NUM_SEG_C];
    __shared__ int   s_wavecnt[MAX_NUM_SEG_C];
    __shared__ int   s_src[MAX_LEN_PAD_C];
    __shared__ float s_lam[MAX_LEN_PAD_C];

    if (tid < MAX_NUM_SEG_C) {
        s_scale[tid]  = scales[b * MAX_NUM_SEG_C + tid] + 0.5f;
        s_lenseg[tid] = len_seg_raw[b * MAX_NUM_SEG_C + tid] + MIN_LEN_SEG_C;
    }
    if (tid < MAX_LEN_PAD_C) {
        s_src[tid] = -1;   // default: invalid slot -> zero output
    }
    __syncthreads();

    const int lseq = len_seq[b];

    // ---- Phase A: per-(segment, grid) mask / source index / lam ----
    // Bit-exact mirror of the reference's f32 arithmetic.
    const float scale = s_scale[wave];
    int offset = 0;
    for (int t = 0; t < wave; ++t) offset += s_lenseg[t];

    const float idx_scaled = (float)lane / scale;      // IEEE f32 div
    const float idx_fl     = floorf(idx_scaled);
    const float lam        = idx_scaled - idx_fl;
    const float idx_org    = idx_fl + (float)offset;

    const bool mask = (idx_fl  < (float)s_lenseg[wave] - 1.0f) &&
                      (idx_org < (float)(lseq - 1));

    // ---- compacted position via ballot + two-level prefix sum ----
    const unsigned long long bal = __ballot(mask);
    if (lane == 0) s_wavecnt[wave] = __popcll(bal);
    __syncthreads();

    int wave_off = 0;
    for (int t = 0; t < wave; ++t) wave_off += s_wavecnt[t];
    const int rank = __popcll(bal & ((1ull << lane) - 1ull));

    if (mask) {
        const int pos = wave_off + rank;
        if (pos < MAX_LEN_PAD_C) {
            int src = (int)idx_org;          // trunc == floor (idx_org >= 0)
            src = min(src, MAX_LEN_PAD_C - 2);
            s_src[pos] = src;
            s_lam[pos] = lam;
        }
    }
    __syncthreads();

    // ---- Phase B: write 192 frames x 20 float4, coalesced ----
    const float4* __restrict__ x4   =
        (const float4*)(x + (size_t)b * MAX_LEN_PAD_C * C_DIM);
    float4* __restrict__ out4 =
        (float4*)(out + (size_t)b * MAX_LEN_PAD_C * C_DIM);

    for (int t = tid; t < MAX_LEN_PAD_C * NQ; t += 448) {
        const int p = t / NQ;
        const int q = t - p * NQ;
        const int src = s_src[p];
        float4 r;
        if (src >= 0) {
            const float lm = s_lam[p];
            const float w0 = 1.0f - lm;
            const float4 a = x4[src * NQ + q];
            const float4 c = x4[(src + 1) * NQ + q];
            r.x = w0 * a.x + lm * c.x;
            r.y = w0 * a.y + lm * c.y;
            r.z = w0 * a.z + lm * c.z;
            r.w = w0 * a.w + lm * c.w;
        } else {
            r = make_float4(0.0f, 0.0f, 0.0f, 0.0f);
        }
        out4[p * NQ + q] = r;
    }
}

extern "C" void kernel_launch(void* const* d_in, const int* in_sizes, int n_in,
                              void* d_out, int out_size, void* d_ws, size_t ws_size,
                              hipStream_t stream) {
    const float* x           = (const float*)d_in[0];
    const int*   len_seq     = (const int*)d_in[1];
    const float* scales      = (const float*)d_in[2];
    const int*   len_seg_raw = (const int*)d_in[3];
    float*       out         = (float*)d_out;

    const int B = in_sizes[1];   // len_seq has one element per batch row

    interp_lnr_kernel<<<B, 448, 0, stream>>>(x, len_seq, scales, len_seg_raw, out);
}

// Round 3
// 394.263 us; speedup vs baseline: 1.0030x; 1.0030x over previous
//
#include <hip/hip_runtime.h>

// Problem constants (from reference)
#define MIN_LEN_SEG_C 19
#define MAX_NUM_SEG_C 7     // 128 // 19 + 1
#define SEG_GRID_C    64
#define MAX_LEN_PAD_C 192
#define C_DIM         80
#define NQ            (C_DIM / 4)        // 20 float4 per frame
#define NTHREADS      448                // 7 waves
#define TOTAL_Q       (MAX_LEN_PAD_C * NQ)   // 3840
#define NITER         ((TOTAL_Q + NTHREADS - 1) / NTHREADS)  // 9 (last partial)

typedef float floatx4 __attribute__((ext_vector_type(4)));  // native vec: ok for nontemporal builtin

// One block per batch row. 448 threads = 7 waves; wave w handles segment w,
// lane i handles grid position i (SEG_GRID == 64 == wavefront size).
__global__ __launch_bounds__(NTHREADS) void interp_lnr_kernel(
    const float* __restrict__ x,          // (B, 192, 80)
    const int*   __restrict__ len_seq,    // (B,)
    const float* __restrict__ scales,     // (B*7,)
    const int*   __restrict__ len_seg_raw,// (B*7,)
    float*       __restrict__ out)        // (B, 192, 80)
{
    const int b    = blockIdx.x;
    const int tid  = threadIdx.x;
    const int wave = tid >> 6;   // segment index 0..6
    const int lane = tid & 63;   // grid index 0..63

    __shared__ float s_scale[MAX_NUM_SEG_C];
    __shared__ int   s_lenseg[MAX_NUM_SEG_C];
    __shared__ int   s_wavecnt[MAX_NUM_SEG_C];
    __shared__ int   s_src[MAX_LEN_PAD_C];
    __shared__ float s_lam[MAX_LEN_PAD_C];

    if (tid < MAX_NUM_SEG_C) {
        s_scale[tid]  = scales[b * MAX_NUM_SEG_C + tid] + 0.5f;
        s_lenseg[tid] = len_seg_raw[b * MAX_NUM_SEG_C + tid] + MIN_LEN_SEG_C;
    }
    if (tid < MAX_LEN_PAD_C) {
        s_src[tid] = -1;   // default: invalid slot -> zero output
    }
    __syncthreads();

    const int lseq = len_seq[b];

    // ---- Phase A: per-(segment, grid) mask / source index / lam ----
    // Bit-exact mirror of the reference's f32 arithmetic.
    const float scale = s_scale[wave];
    int offset = 0;
    for (int t = 0; t < wave; ++t) offset += s_lenseg[t];

    const float idx_scaled = (float)lane / scale;      // IEEE f32 div
    const float idx_fl     = floorf(idx_scaled);
    const float lam        = idx_scaled - idx_fl;
    const float idx_org    = idx_fl + (float)offset;

    const bool mask = (idx_fl  < (float)s_lenseg[wave] - 1.0f) &&
                      (idx_org < (float)(lseq - 1));

    // ---- compacted position via ballot + two-level prefix sum ----
    const unsigned long long bal = __ballot(mask);
    if (lane == 0) s_wavecnt[wave] = __popcll(bal);
    __syncthreads();

    int wave_off = 0;
    for (int t = 0; t < wave; ++t) wave_off += s_wavecnt[t];
    const int rank = __popcll(bal & ((1ull << lane) - 1ull));

    if (mask) {
        const int pos = wave_off + rank;
        if (pos < MAX_LEN_PAD_C) {
            int src = (int)idx_org;          // trunc == floor (idx_org >= 0)
            src = min(src, MAX_LEN_PAD_C - 2);
            s_src[pos] = src;
            s_lam[pos] = lam;
        }
    }
    __syncthreads();

    // ---- Phase B: write 192 frames x 20 float4, coalesced ----
    // Batched LDS map reads -> 18 outstanding gather loads -> lerp ->
    // nontemporal store (output is streaming write-once; keep L2 for gathers).
    const floatx4* __restrict__ x4 =
        (const floatx4*)(x + (size_t)b * MAX_LEN_PAD_C * C_DIM);
    floatx4* __restrict__ out4 =
        (floatx4*)(out + (size_t)b * MAX_LEN_PAD_C * C_DIM);

    int   srcs[NITER];
    float lams[NITER];
    int   qs[NITER];

    #pragma unroll
    for (int i = 0; i < NITER; ++i) {
        const int t = tid + i * NTHREADS;
        if (t < TOTAL_Q) {
            const int p = t / NQ;
            qs[i]   = t - p * NQ;
            srcs[i] = s_src[p];
            lams[i] = s_lam[p];
        } else {
            srcs[i] = -2;   // out of range: no store at all
            qs[i]   = 0;
            lams[i] = 0.0f;
        }
    }

    floatx4 va[NITER], vc[NITER];
    #pragma unroll
    for (int i = 0; i < NITER; ++i) {
        if (srcs[i] >= 0) {
            const int base = srcs[i] * NQ + qs[i];
            va[i] = x4[base];
            vc[i] = x4[base + NQ];
        }
    }

    #pragma unroll
    for (int i = 0; i < NITER; ++i) {
        const int t = tid + i * NTHREADS;
        if (srcs[i] >= -1) {   // t < TOTAL_Q
            floatx4 r = (floatx4)(0.0f);
            if (srcs[i] >= 0) {
                const float lm = lams[i];
                const float w0 = 1.0f - lm;
                r = w0 * va[i] + lm * vc[i];
            }
            __builtin_nontemporal_store(r, &out4[t]);
        }
    }
}

extern "C" void kernel_launch(void* const* d_in, const int* in_sizes, int n_in,
                              void* d_out, int out_size, void* d_ws, size_t ws_size,
                              hipStream_t stream) {
    const float* x           = (const float*)d_in[0];
    const int*   len_seq     = (const int*)d_in[1];
    const float* scales      = (const float*)d_in[2];
    const int*   len_seg_raw = (const int*)d_in[3];
    float*       out         = (float*)d_out;

    const int B = in_sizes[1];   // len_seq has one element per batch row

    interp_lnr_kernel<<<B, NTHREADS, 0, stream>>>(x, len_seq, scales, len_seg_raw, out);
}